// Round 13
// baseline (130.186 us; speedup 1.0000x reference)
//
#include <hip/hip_runtime.h>

#define BTOT 8192
#define TT 512
#define LOG2E 1.44269504089f

__device__ __forceinline__ float exp2_f(float x) { return __builtin_amdgcn_exp2f(x); }

// soft reciprocal: magic seed + 2 Newton -> ~1e-6 rel err, 5 VALU instr, dep ~20cy.
// valid for normal-range d>0 (inputs clamped via fmed3(+-30) upstream).
__device__ __forceinline__ float srcp(float d) {
    float r = __int_as_float(0x7EF311C3 - __float_as_int(d));
    r = r * fmaf(-d, r, 2.0f);
    r = r * fmaf(-d, r, 2.0f);
    return r;
}

// DPP row shifts (validated R5/R11, both passed at bf16 floor):
//   ctrl 0x100+m : dst[i] = src[i+m]; ctrl 0x110+m : dst[i] = src[i-m]
// bound_ctrl=true -> OOB lanes read 0; always multiplied by a zero weight anyway.
template<int CTRL>
__device__ __forceinline__ float dppf(float v) {
    return __int_as_float(__builtin_amdgcn_mov_dpp(__float_as_int(v), CTRL, 0xf, 0xf, true));
}

__global__ __launch_bounds__(64, 1) void lstm_kernel(
    const float* __restrict__ x,
    const float* __restrict__ W_ih,
    const float* __restrict__ W_hh,
    const float* __restrict__ b_ih,
    const float* __restrict__ b_hh,
    const float* __restrict__ fc1_w,
    const float* __restrict__ fc1_b,
    const float* __restrict__ fc2_w,
    const float* __restrict__ fc2_b,
    float* __restrict__ out)
{
    const int lane  = threadIdx.x;             // one wave per block
    const int u_raw = lane & 7;                // slot in octet
    const int u     = (u_raw < 5) ? u_raw : 0; // pad lanes alias unit 0 (finite, zero-weighted by neighbors)
    const int b     = blockIdx.x * 8 + (lane >> 3);   // 1024*8 = 8192 exact
    const bool wr   = (u_raw == 0);

    // Lane owns all 4 gate rows (i,f,g,o) of unit u -> activations & cell are lane-local.
    // Scaling folded into weights (proven R6/R12 math):
    //  i,f,o (r!=2): acc = -z*log2e          -> sigmoid(z) = srcp(1+2^acc)
    //  g     (r==2): acc =  2z*log2e         -> val = 2L*tanh(z) = fma(-4L, srcp(1+2^acc), 2L)
    // so the cell accumulates C = 2L*c and tanh(c) = 1 - 2*srcp(1+2^C) directly.
    float wih[4][5], bias[4];
    float wp[4][9];   // recurrent weights by DPP shift d=k-u (index d+4), zero-padded
    #pragma unroll
    for (int r = 0; r < 4; ++r) {
        const float s = (r == 2) ? (2.0f * LOG2E) : (-LOG2E);
        const int row = r * 5 + u;             // PyTorch gate-major
        #pragma unroll
        for (int i = 0; i < 5; ++i) wih[r][i] = s * W_ih[row * 5 + i];
        bias[r] = s * (b_ih[row] + b_hh[row]);
        #pragma unroll
        for (int d = -4; d <= 4; ++d) {
            const int k = u + d;
            wp[r][d + 4] = (k >= 0 && k <= 4) ? s * W_hh[row * 5 + k] : 0.0f;
        }
    }

    const float* xb = x + (size_t)b * (TT * 5);

    float h = 0.0f, C = 0.0f;

    float4 bufA[5], bufB[5];
    #pragma unroll
    for (int i = 0; i < 5; ++i) {
        bufA[i] = *(const float4*)(xb + 0  + 4 * i);   // t = 0..3
        bufB[i] = *(const float4*)(xb + 20 + 4 * i);   // t = 4..7
    }

    auto process4 = [&](const float4* buf) {
        float xs[20];
        *(float4*)&xs[0]  = buf[0];
        *(float4*)&xs[4]  = buf[1];
        *(float4*)&xs[8]  = buf[2];
        *(float4*)&xs[12] = buf[3];
        *(float4*)&xs[16] = buf[4];

        // x-projections for 4 steps x 4 gates up-front: 80 independent FMAs of ILP
        // that also serve as stall filler for the serial segment below.
        float gx[4][4];
        #pragma unroll
        for (int s = 0; s < 4; ++s)
            #pragma unroll
            for (int r = 0; r < 4; ++r) {
                float a = bias[r];
                #pragma unroll
                for (int i = 0; i < 5; ++i) a = fmaf(wih[r][i], xs[s * 5 + i], a);
                gx[s][r] = a;
            }

        #pragma unroll
        for (int s = 0; s < 4; ++s) {
            // 8 DPP shifts of h, shared by all 4 gate dots (no LDS anywhere)
            const float sp1 = dppf<0x101>(h);
            const float sp2 = dppf<0x102>(h);
            const float sp3 = dppf<0x103>(h);
            const float sp4 = dppf<0x104>(h);
            const float sm1 = dppf<0x111>(h);
            const float sm2 = dppf<0x112>(h);
            const float sm3 = dppf<0x113>(h);
            const float sm4 = dppf<0x114>(h);

            // recurrent dots, two parallel fma chains per gate (depth ~5 fma)
            float z[4];
            #pragma unroll
            for (int r = 0; r < 4; ++r) {
                float a = gx[s][r];
                a = fmaf(wp[r][0], sm4, a);
                a = fmaf(wp[r][1], sm3, a);
                a = fmaf(wp[r][2], sm2, a);
                a = fmaf(wp[r][3], sm1, a);
                float bsum = wp[r][4] * h;
                bsum = fmaf(wp[r][5], sp1, bsum);
                bsum = fmaf(wp[r][6], sp2, bsum);
                bsum = fmaf(wp[r][7], sp3, bsum);
                bsum = fmaf(wp[r][8], sp4, bsum);
                z[r] = a + bsum;
            }

            // 4 activation sites: hw exp2 (1 instr) + soft rcp (5 instr), parallel
            float val[4];
            #pragma unroll
            for (int r = 0; r < 4; ++r) {
                const float t = __builtin_amdgcn_fmed3f(z[r], -30.0f, 30.0f);
                const float rr = srcp(1.0f + exp2_f(t));
                if (r == 2) val[r] = fmaf(-4.0f * LOG2E, rr, 2.0f * LOG2E); // 2L*tanh(z)
                else        val[r] = rr;                                     // sigmoid(z)
            }

            // cell update (C = 2L*c) + output tanh — the only serial segment
            C = fmaf(val[1], C, val[0] * val[2]);
            const float t2 = __builtin_amdgcn_fmed3f(C, -30.0f, 30.0f);
            const float r2 = srcp(1.0f + exp2_f(t2));
            h = val[3] * fmaf(-2.0f, r2, 1.0f);   // lane u holds h_u
        }
    };

    for (int t0 = 0; t0 < TT; t0 += 8) {
        process4(bufA);                                // steps t0 .. t0+3
        {
            const int tld = (t0 + 8 <= TT - 4) ? (t0 + 8) : (TT - 4);
            const float* p = xb + tld * 5;
            #pragma unroll
            for (int i = 0; i < 5; ++i) bufA[i] = *(const float4*)(p + 4 * i);
        }
        process4(bufB);                                // steps t0+4 .. t0+7
        {
            const int tld = (t0 + 12 <= TT - 4) ? (t0 + 12) : (TT - 4);
            const float* p = xb + tld * 5;
            #pragma unroll
            for (int i = 0; i < 5; ++i) bufB[i] = *(const float4*)(p + 4 * i);
        }
    }

    // gather h_1..h_4 onto the u==0 lane (in-row reads, +1..+4)
    const float g1 = dppf<0x101>(h);
    const float g2 = dppf<0x102>(h);
    const float g3 = dppf<0x103>(h);
    const float g4 = dppf<0x104>(h);

    if (wr) {
        float p = fc1_b[0];
        float v = fc2_b[0];
        p = fmaf(fc1_w[0], h,  p);  v = fmaf(fc2_w[0], h,  v);
        p = fmaf(fc1_w[1], g1, p);  v = fmaf(fc2_w[1], g1, v);
        p = fmaf(fc1_w[2], g2, p);  v = fmaf(fc2_w[2], g2, v);
        p = fmaf(fc1_w[3], g3, p);  v = fmaf(fc2_w[3], g3, v);
        p = fmaf(fc1_w[4], g4, p);  v = fmaf(fc2_w[4], g4, v);
        out[b] = p;
        out[BTOT + b] = v;
    }
}

extern "C" void kernel_launch(void* const* d_in, const int* in_sizes, int n_in,
                              void* d_out, int out_size, void* d_ws, size_t ws_size,
                              hipStream_t stream) {
    const float* x     = (const float*)d_in[0];
    const float* W_ih  = (const float*)d_in[1];
    const float* W_hh  = (const float*)d_in[2];
    const float* b_ih  = (const float*)d_in[3];
    const float* b_hh  = (const float*)d_in[4];
    const float* fc1_w = (const float*)d_in[5];
    const float* fc1_b = (const float*)d_in[6];
    const float* fc2_w = (const float*)d_in[7];
    const float* fc2_b = (const float*)d_in[8];
    float* out = (float*)d_out;

    const int blocks = BTOT / 8;   // 1024 one-wave blocks, 8 batches each -> K=1, every SIMD busy
    lstm_kernel<<<blocks, 64, 0, stream>>>(x, W_ih, W_hh, b_ih, b_hh,
                                           fc1_w, fc1_b, fc2_w, fc2_b, out);
}